// Round 1
// 72.063 us; speedup vs baseline: 1.0087x; 1.0087x over previous
//
#include <hip/hip_runtime.h>

#define W  1280
#define H  384
#define ND 21     // MAXDISP
#define BT 320    // 4 columns per thread
#define R  4      // rows per block (H % R == 0)

// Per output column c (DIR=+1 == maskl, bs<0):
//   base = (C[c] + C[c+DIR]) / 6
//   mask = clip( min_i |base + (i+1) - C[c+DIR*(2+i)]/3| , 0, 1)
// C = 3-row column sum (rows edge-clamped; columns edge-clamped both ends).
//
// FAST PATH (guarded, block-uniform): if every colsum C in the row window is
// <= 3 (i.e. disp <= 1, true for the bench's uniform[0,1) input), then for
// i >= 1: term_i = base + (i+1) - C/3 >= (i+1) - 1 = i >= 1, so
// clip(min_i |term_i|, 0, 1) == min(|term_0|, 1). One term per pixel.
// Guard: __syncthreads_or over per-thread max of its colsums (halo sums
// duplicate edge columns already covered by threads 0/319).

template <int DIR>
__device__ __forceinline__ void compute_row_fast(const float* __restrict__ Cs,
                                                 float* __restrict__ orow, int t) {
    // DIR>0: need C[4t .. 4t+5];  DIR<0: need C[4t-2 .. 4t+3].
    const float4* p = (const float4*)(Cs + ((DIR > 0) ? 4 * t : 4 * t - 4));
    float4 f0 = p[0], f1 = p[1];
    float V[8] = {f0.x, f0.y, f0.z, f0.w, f1.x, f1.y, f1.z, f1.w};
    float4 o; float* op = &o.x;
    #pragma unroll
    for (int j = 0; j < 4; j++) {
        // DIR>0: V[m] = C[4t+m]   -> C[c]=V[j],   C[c+1]=V[j+1], C[c+2]=V[j+2]
        // DIR<0: V[m] = C[4t-4+m] -> C[c]=V[j+4], C[c-1]=V[j+3], C[c-2]=V[j+2]
        float term = (DIR > 0)
            ? (V[j]     + V[j + 1]) * (1.0f / 6.0f) - V[j + 2] * (1.0f / 3.0f) + 1.0f
            : (V[j + 4] + V[j + 3]) * (1.0f / 6.0f) - V[j + 2] * (1.0f / 3.0f) + 1.0f;
        op[j] = fminf(fabsf(term), 1.0f);
    }
    ((float4*)orow)[t] = o;
}

// General path: identical to the previously-verified 21-term kernel.
// Strength-reduced: term(j,m) = B_j + Q[m], m = j..j+20, where
//   DIR>0: Q[m] = (m+1)  - V[m+2]/3,  B_j = (V[j]+V[j+1])/6   - j
//   DIR<0: Q[m] = (21-m) - V[m+2]/3,  B_j = (V[24+j]+V[23+j])/6 + j
template <int DIR>
__device__ __forceinline__ void compute_row_general(const float* __restrict__ Cs,
                                                    float* __restrict__ orow, int t) {
    float V[28];
    const float4* p = (const float4*)(Cs + ((DIR > 0) ? 4 * t : 4 * t - 24));
    #pragma unroll
    for (int m = 0; m < 7; m++) {
        float4 f = p[m];
        V[4*m+0] = f.x; V[4*m+1] = f.y; V[4*m+2] = f.z; V[4*m+3] = f.w;
    }
    float Q[24];
    #pragma unroll
    for (int m = 0; m < 24; m++) {
        float k = (DIR > 0) ? (float)(m + 1) : (float)(21 - m);
        Q[m] = k - V[m + 2] * (1.0f / 3.0f);
    }
    float4 o; float* op = &o.x;
    #pragma unroll
    for (int j = 0; j < 4; j++) {
        float base = (DIR > 0) ? (V[j] + V[j+1]) * (1.0f / 6.0f)
                               : (V[24+j] + V[23+j]) * (1.0f / 6.0f);
        float B = (DIR > 0) ? (base - (float)j) : (base + (float)j);
        float m0 = 1e30f;
        #pragma unroll
        for (int i = 0; i < ND; i++)
            m0 = fminf(m0, fabsf(B + Q[j + i]));
        op[j] = fminf(m0, 1.0f);   // m0 >= 0, so clip(0,1) == min(.,1)
    }
    ((float4*)orow)[t] = o;
}

template <int DIR>
__device__ __forceinline__ void run_rows(const float* __restrict__ dbase,
                                         float* __restrict__ outb,
                                         float (*Cbuf)[W + 48],
                                         int rs, int t) {
    const bool lp = (t < 24);
    const bool rp = (t >= 32 && t < 56);
    const int  ecol = lp ? 0 : (W - 1);

    // Rolling registers: rows r-1, r, r+1 for current output row r.
    int r0 = max(rs - 1, 0);
    float4 a = ((const float4*)(dbase + (size_t)r0       * W))[t];
    float4 b = ((const float4*)(dbase + (size_t)rs       * W))[t];
    float4 c = ((const float4*)(dbase + (size_t)(rs + 1) * W))[t];
    float4 d = {0, 0, 0, 0};
    float ea = 0, eb = 0, ec = 0, ed = 0;
    if (lp || rp) {
        ea = dbase[(size_t)r0       * W + ecol];
        eb = dbase[(size_t)rs       * W + ecol];
        ec = dbase[(size_t)(rs + 1) * W + ecol];
    }

    #pragma unroll
    for (int r = 0; r < R; r++) {
        float* Cs = Cbuf[r & 1] + 24;
        float4 s;
        s.x = a.x + b.x + c.x; s.y = a.y + b.y + c.y;
        s.z = a.z + b.z + c.z; s.w = a.w + b.w + c.w;
        ((float4*)Cs)[t] = s;
        if (lp)      Cs[t - 24]       = ea + eb + ec;
        else if (rp) Cs[W + (t - 32)] = ea + eb + ec;

        // Prefetch next input row before the barrier.
        if (r + 1 < R) {
            int nr = min(rs + r + 2, H - 1);
            d = ((const float4*)(dbase + (size_t)nr * W))[t];
            if (lp || rp) ed = dbase[(size_t)nr * W + ecol];
        }

        // Barrier + block-wide range check (fast-path validity: all C <= 3).
        float mx = fmaxf(fmaxf(s.x, s.y), fmaxf(s.z, s.w));
        int any_big = __syncthreads_or(mx > 3.0f);

        if (!any_big) compute_row_fast<DIR>(Cs, outb + (size_t)r * W, t);
        else          compute_row_general<DIR>(Cs, outb + (size_t)r * W, t);

        a = b; b = c; c = d;
        ea = eb; eb = ec; ec = ed;
    }
}

__global__ __launch_bounds__(BT) void occl_kernel(const float* __restrict__ disp,
                                                  const float* __restrict__ bsl,
                                                  float* __restrict__ out) {
    // XCD swizzle: HW maps block g -> XCD (g % 8). Remap so XCD k owns batch k
    // (96 consecutive row-blocks): its 1.97 MB input fits the per-XCD 4 MB L2,
    // so the 1.5x row re-reads hit L2, not HBM.
    int g = blockIdx.x, nb = gridDim.x;
    int id = (nb & 7) ? g : ((g & 7) * (nb >> 3) + (g >> 3));
    const int RB = H / R;
    const int batch = id / RB;
    const int rs = (id % RB) * R;
    const float bs = bsl[batch];
    const int t = threadIdx.x;
    float* outb = out + ((size_t)batch * H + rs) * W;

    if (bs == 0.0f) {
        float4 z = {0, 0, 0, 0};
        #pragma unroll
        for (int r = 0; r < R; r++) ((float4*)(outb + (size_t)r * W))[t] = z;
        return;
    }

    __shared__ float Cbuf[2][W + 48];   // double-buffered colsums, idx -24..W+23
    const float* dbase = disp + (size_t)batch * H * W;

    if (bs < 0.0f) run_rows<1>(dbase, outb, Cbuf, rs, t);
    else           run_rows<-1>(dbase, outb, Cbuf, rs, t);
}

extern "C" void kernel_launch(void* const* d_in, const int* in_sizes, int n_in,
                              void* d_out, int out_size, void* d_ws, size_t ws_size,
                              hipStream_t stream) {
    const float* disp = (const float*)d_in[0];
    const float* bsl  = (const float*)d_in[1];
    float* out        = (float*)d_out;
    const int n_batch = in_sizes[1];  // bsline: one entry per batch

    occl_kernel<<<dim3(n_batch * (H / R)), BT, 0, stream>>>(disp, bsl, out);
}